// Round 1
// baseline (78.038 us; speedup 1.0000x reference)
//
#include <hip/hip_runtime.h>

#define TIMESTEPS 1000
#define NROWS 16384                 // 64 batch * 256 H rows
#define ROWS_PER_WAVE 4
#define WAVES_PER_BLOCK 4
#define NBLOCKS (NROWS / (ROWS_PER_WAVE * WAVES_PER_BLOCK))   // 1024
#define NPARTIALS (NROWS / ROWS_PER_WAVE)                     // 4096
#define TOTAL_ELEMS 16384000.0      // 64 * 1 * 256 * 1000

// Wave-synchronous: each 64-lane wave owns a private 2048-int LDS region
// (R bins at [0..999], T bins at [1024..2023], rest zero padding) and
// processes ROWS_PER_WAVE rows with NO __syncthreads. DS ops from a single
// wave complete in order; wave_barrier() pins compiler instruction order.
//
// v2 change vs. 75.8us baseline: ALL 8 global loads (4 rows x rec+tgt) are
// issued at kernel entry into registers; the row loop is fully unrolled so
// the float4 arrays stay in VGPRs (static indexing). This removes the
// per-row vmcnt(0) stall (~700cy HBM latency serialized 4x per wave under
// the old '#pragma unroll 1' structure) and lets the LDS pipe run at its
// throughput limit. launch_bounds(256,4) caps VGPR at 128 -> 16 waves/CU.
__global__ __launch_bounds__(256, 4) void holo_row_loss(
    const float* __restrict__ rec,
    const float* __restrict__ tgt,
    float* __restrict__ partials)
{
    __shared__ int bins[WAVES_PER_BLOCK][2048];   // 32 KiB

    const int tid  = threadIdx.x;
    const int wav  = tid >> 6;
    const int lane = tid & 63;
    const int gw   = blockIdx.x * WAVES_PER_BLOCK + wav;   // global wave id

    int* __restrict__ binw = &bins[wav][0];

    const float4* rec4 = (const float4*)rec;
    const float4* tgt4 = (const float4*)tgt;
    const int base = gw * ROWS_PER_WAVE * 64 + lane;

    // Issue every global load up front: rows become register-resident and
    // rows 1..3's HBM latency hides under row 0..2's LDS work.
    float4 xr[ROWS_PER_WAVE], xt[ROWS_PER_WAVE];
#pragma unroll
    for (int r = 0; r < ROWS_PER_WAVE; ++r) {
        xr[r] = rec4[base + r * 64];
        xt[r] = tgt4[base + r * 64];
    }

    // zero this wave's 2048 ints while the loads are in flight
    int4 z4; z4.x = 0; z4.y = 0; z4.z = 0; z4.w = 0;
    int4* zb = (int4*)binw;
#pragma unroll
    for (int j = 0; j < 8; ++j) zb[j * 64 + lane] = z4;
    __builtin_amdgcn_wave_barrier();

    float s = 0.0f;   // exact: integer-valued partial stays < 2^24 per lane

#pragma unroll
    for (int r = 0; r < ROWS_PER_WAVE; ++r) {
        int qr[4], qt[4];
#pragma unroll
        for (int j = 0; j < 4; ++j) {
            const float vr = (&xr[r].x)[j];
            const float vt = (&xt[r].x)[j];
            const int   w  = lane * 4 + j;
            // q = (int(x*1000) - 1) mod 1000, x==0 dropped. f32 mul + trunc
            // matches jnp astype(int32); q in [-1, 998] for x in [0,1).
            int q = (int)(vr * 1000.0f) - 1;
            if (q < 0) q += TIMESTEPS;
            if (vr != 0.0f) { atomicMax(&binw[q], w); qr[j] = q; }
            else            { qr[j] = 1012; }          // pad slot, stays 0
            q = (int)(vt * 1000.0f) - 1;
            if (q < 0) q += TIMESTEPS;
            if (vt != 0.0f) { atomicMax(&binw[1024 + q], w); qt[j] = q; }
            else            { qt[j] = 1012; }
        }
        __builtin_amdgcn_wave_barrier();

        // sum phase: lane reads 4+4 int4 (stride-16B), diff^2 accumulate.
        // pad bins [1000..1023] are 0 in both halves -> contribute 0.
        const int4* r4 = (const int4*)binw;
        const int4* t4 = (const int4*)(binw + 1024);
#pragma unroll
        for (int k = 0; k < 4; ++k) {
            const int4 a = r4[k * 64 + lane];
            const int4 b = t4[k * 64 + lane];
            const float d0 = (float)(a.x - b.x);
            const float d1 = (float)(a.y - b.y);
            const float d2 = (float)(a.z - b.z);
            const float d3 = (float)(a.w - b.w);
            s = fmaf(d0, d0, s);
            s = fmaf(d1, d1, s);
            s = fmaf(d2, d2, s);
            s = fmaf(d3, d3, s);
        }
        __builtin_amdgcn_wave_barrier();

        // re-zero ONLY the bins this lane scattered to (dup writes of 0 ok).
        // LDS ops from one wave complete in order, so these are guaranteed
        // to land before the next row's atomics without any wait.
#pragma unroll
        for (int j = 0; j < 4; ++j) {
            binw[qr[j]] = 0;
            binw[1024 + qt[j]] = 0;
        }
        __builtin_amdgcn_wave_barrier();
    }

    // one shuffle reduce per wave (order kept identical for bit-exactness)
    for (int off = 32; off > 0; off >>= 1) s += __shfl_down(s, off, 64);
    if (lane == 0) partials[gw] = s;
}

// Deterministic final reduction. float4 loads (4x fewer instrs); double
// accumulation of integer-valued f32 partials is exact in any order, so
// the result stays bit-identical to the verified baseline.
__global__ __launch_bounds__(256) void reduce_partials(
    const float* __restrict__ partials,
    float* __restrict__ out)
{
    __shared__ double wave_sums[4];
    const int tid = threadIdx.x;
    const float4* p4 = (const float4*)partials;
    double s = 0.0;
#pragma unroll
    for (int i = 0; i < NPARTIALS / 1024; ++i) {      // 4 iterations
        const float4 v = p4[i * 256 + tid];
        s += (double)v.x + (double)v.y + (double)v.z + (double)v.w;
    }
    for (int off = 32; off > 0; off >>= 1) s += __shfl_down(s, off, 64);
    if ((tid & 63) == 0) wave_sums[tid >> 6] = s;
    __syncthreads();
    if (tid == 0) {
        double tot = wave_sums[0] + wave_sums[1] + wave_sums[2] + wave_sums[3];
        out[0] = (float)(tot / TOTAL_ELEMS);
    }
}

extern "C" void kernel_launch(void* const* d_in, const int* in_sizes, int n_in,
                              void* d_out, int out_size, void* d_ws, size_t ws_size,
                              hipStream_t stream)
{
    const float* rec = (const float*)d_in[0];
    const float* tgt = (const float*)d_in[1];
    float* out = (float*)d_out;
    float* partials = (float*)d_ws;        // NPARTIALS * 4 = 16 KiB

    holo_row_loss<<<NBLOCKS, 256, 0, stream>>>(rec, tgt, partials);
    reduce_partials<<<1, 256, 0, stream>>>(partials, out);
}

// Round 2
// 77.962 us; speedup vs baseline: 1.0010x; 1.0010x over previous
//
#include <hip/hip_runtime.h>

#define TIMESTEPS 1000
#define NROWS 16384                        // 64 batch * 256 H rows
#define ROWS_PER_BLOCK 8
#define NBLOCKS (NROWS / ROWS_PER_BLOCK)   // 2048
#define TOTAL_ELEMS 16384000.0             // 64 * 1 * 256 * 1000

// v3: block-shared bins. One 256-thread block owns ONE 2048-int LDS bin
// region (rec bins [0..999] at [0..1023], tgt at [1024..2047], pads zero)
// and processes 8 rows. Thread t IS column w=t: one rec + one tgt value
// per row, so the atomicMax value is just tid. 8 KiB LDS/block -> 8
// blocks/CU = 32 waves/CU (2x the wave-private v1/v2 design), and each
// per-row dependency chain (2 atomics -> 2 b128 reads -> 2 b128 rezero
// writes per thread) is 4x shorter. Sweep-rezero: thread t rewrites only
// the int4 slots that only thread t reads, so no barrier is needed
// between scan and rezero -> 2 __syncthreads per row.
// All accumulation is exact int32 (per-thread <= 8*4*255^2 ~ 2.1e6,
// block <= 5.3e8 < 2^31), so partials are bit-exact in any order.
__global__ __launch_bounds__(256, 8) void holo_block_loss(
    const float* __restrict__ rec,
    const float* __restrict__ tgt,
    int* __restrict__ partials)
{
    __shared__ __align__(16) int bins[2048];   // 8 KiB
    __shared__ int wsum[4];

    const int tid  = threadIdx.x;              // == column index w
    const int base = blockIdx.x * (ROWS_PER_BLOCK * 256) + tid;

    // prefetch all 8 rows x {rec,tgt}: 16 coalesced scalar loads in flight
    float rv[ROWS_PER_BLOCK], tv[ROWS_PER_BLOCK];
#pragma unroll
    for (int r = 0; r < ROWS_PER_BLOCK; ++r) {
        rv[r] = rec[base + r * 256];
        tv[r] = tgt[base + r * 256];
    }

    // zero bins: 2 x int4 per thread while loads are in flight
    int4 z4; z4.x = 0; z4.y = 0; z4.z = 0; z4.w = 0;
    int4* zb = (int4*)bins;
    zb[tid]       = z4;
    zb[256 + tid] = z4;

    int s = 0;
    __syncthreads();

#pragma unroll
    for (int r = 0; r < ROWS_PER_BLOCK; ++r) {
        const float vr = rv[r];
        const float vt = tv[r];
        // q = (int(x*1000) - 1) mod 1000, x==0 dropped. f32 mul + trunc
        // matches jnp astype(int32); q in [-1, 998] for x in [0,1).
        int q = (int)(vr * 1000.0f) - 1;
        if (q < 0) q += TIMESTEPS;
        if (vr != 0.0f) atomicMax(&bins[q], tid);
        q = (int)(vt * 1000.0f) - 1;
        if (q < 0) q += TIMESTEPS;
        if (vt != 0.0f) atomicMax(&bins[1024 + q], tid);
        __syncthreads();

        // scan: thread t handles bins 4t..4t+3 of both halves (pads are
        // zero in both halves -> contribute 0), then sweep-rezeroes its
        // own int4 slots. Only thread t ever reads slots t / 256+t in
        // this phase, so read->write needs no inter-thread barrier; the
        // trailing __syncthreads orders rezero vs next row's scatter.
        const int4 a = ((const int4*)bins)[tid];
        const int4 b = ((const int4*)bins)[256 + tid];
        zb[tid]       = z4;
        zb[256 + tid] = z4;
        int d;
        d = a.x - b.x; s += d * d;
        d = a.y - b.y; s += d * d;
        d = a.z - b.z; s += d * d;
        d = a.w - b.w; s += d * d;
        __syncthreads();
    }

    // exact int32 block reduction: wave shuffle tree + 4-way LDS combine
    for (int off = 32; off > 0; off >>= 1) s += __shfl_down(s, off, 64);
    if ((tid & 63) == 0) wsum[tid >> 6] = s;
    __syncthreads();
    if (tid == 0)
        partials[blockIdx.x] = wsum[0] + wsum[1] + wsum[2] + wsum[3];
}

// Deterministic final reduction: 2048 exact int partials -> double -> mean.
__global__ __launch_bounds__(256) void reduce_partials(
    const int* __restrict__ partials,
    float* __restrict__ out)
{
    __shared__ double wave_sums[4];
    const int tid = threadIdx.x;
    const int4* p4 = (const int4*)partials;   // 2048 ints = 512 int4
    const int4 u = p4[tid & 255];
    const int4 v = p4[256 + (tid & 255)];
    double s = 0.0;
    if (tid < 256) {
        s = (double)u.x + (double)u.y + (double)u.z + (double)u.w
          + (double)v.x + (double)v.y + (double)v.z + (double)v.w;
    }
    for (int off = 32; off > 0; off >>= 1) s += __shfl_down(s, off, 64);
    if ((tid & 63) == 0) wave_sums[tid >> 6] = s;
    __syncthreads();
    if (tid == 0) {
        double tot = wave_sums[0] + wave_sums[1] + wave_sums[2] + wave_sums[3];
        out[0] = (float)(tot / TOTAL_ELEMS);
    }
}

extern "C" void kernel_launch(void* const* d_in, const int* in_sizes, int n_in,
                              void* d_out, int out_size, void* d_ws, size_t ws_size,
                              hipStream_t stream)
{
    const float* rec = (const float*)d_in[0];
    const float* tgt = (const float*)d_in[1];
    float* out = (float*)d_out;
    int* partials = (int*)d_ws;                // NBLOCKS * 4 = 8 KiB

    holo_block_loss<<<NBLOCKS, 256, 0, stream>>>(rec, tgt, partials);
    reduce_partials<<<1, 256, 0, stream>>>(partials, out);
}

// Round 3
// 77.166 us; speedup vs baseline: 1.0113x; 1.0103x over previous
//
#include <hip/hip_runtime.h>

#define TIMESTEPS 1000
#define NROWS 16384                        // 64 batch * 256 H rows
#define ROWS_PER_BLOCK 8
#define NBLOCKS (NROWS / ROWS_PER_BLOCK)   // 2048
#define TOTAL_ELEMS 16384000.0             // 64 * 1 * 256 * 1000

// v4: epoch-tagged ping-pong bins — eliminates the per-row rezero pass.
//
// Scatter stores key = ((r+1)<<8) | w via atomicMax. Within one row all
// keys share the epoch prefix (r+1), so max over keys == max over w.
// Entries left over from earlier rows have a SMALLER epoch and are
// filtered at scan time: w = (v>>8)==r+1 ? v&255 : 0. Bins are zeroed
// once (epoch 0 matches no row) and never rewritten. This removes the
// 512 b128 rezero wave-instrs/CU (~6K LDS-pipe cycles) of v3.
//
// Two regions ping-pong (r&1): scatter(r+1) overlaps scan(r) in the same
// phase (different regions), giving ONE __syncthreads per row. Hazard
// check: scan(r) reads bins[r&1]; the next writer of bins[r&1] is
// scatter(r+2), which lies behind barrier r+1 -> ordered. 16 KiB LDS ->
// still 8 blocks/CU (32 waves/CU).
//
// Accumulation is exact int32: per-thread s <= 8 rows * 4 diffs * 255^2
// ~ 2.1e6; block sum <= 5.3e8 < 2^31 -> bit-exact in any order.
__global__ __launch_bounds__(256, 8) void holo_block_loss(
    const float* __restrict__ rec,
    const float* __restrict__ tgt,
    int* __restrict__ partials)
{
    __shared__ __align__(16) int bins[2][2048];   // 16 KiB ping-pong
    __shared__ int wsum[4];

    const int tid  = threadIdx.x;              // == column index w
    const int base = blockIdx.x * (ROWS_PER_BLOCK * 256) + tid;

    // prefetch all 8 rows x {rec,tgt}: 16 coalesced loads in flight
    float rv[ROWS_PER_BLOCK], tv[ROWS_PER_BLOCK];
#pragma unroll
    for (int r = 0; r < ROWS_PER_BLOCK; ++r) {
        rv[r] = rec[base + r * 256];
        tv[r] = tgt[base + r * 256];
    }

    // zero BOTH regions once (4 int4/thread) while loads are in flight
    int4 z4; z4.x = 0; z4.y = 0; z4.z = 0; z4.w = 0;
    int4* zb = (int4*)&bins[0][0];
#pragma unroll
    for (int j = 0; j < 4; ++j) zb[j * 256 + tid] = z4;

    int s = 0;
    __syncthreads();

#pragma unroll
    for (int r = 0; r < ROWS_PER_BLOCK; ++r) {
        int* __restrict__ reg = &bins[r & 1][0];   // r compile-time (unrolled)
        const int epoch = (r + 1) << 8;

        // scatter this row (overlaps with scan of row r-1 on the LDS pipe)
        const float vr = rv[r];
        const float vt = tv[r];
        // q = (int(x*1000) - 1) mod 1000, x==0 dropped. f32 mul + trunc
        // matches jnp astype(int32); q in [-1, 998] for x in [0,1).
        int q = (int)(vr * 1000.0f) - 1;
        if (q < 0) q += TIMESTEPS;
        if (vr != 0.0f) atomicMax(&reg[q], epoch | tid);
        q = (int)(vt * 1000.0f) - 1;
        if (q < 0) q += TIMESTEPS;
        if (vt != 0.0f) atomicMax(&reg[1024 + q], epoch | tid);
        __syncthreads();

        // scan: thread t reads int4 slots t (rec half) and 256+t (tgt
        // half); stale/empty entries carry a foreign epoch -> w = 0.
        // Pads [1000..1023] are never scattered to -> epoch 0 -> 0.
        const int4 a = ((const int4*)reg)[tid];
        const int4 b = ((const int4*)reg)[256 + tid];
        const int e = r + 1;
        int wa, wb, d;
        wa = ((a.x >> 8) == e) ? (a.x & 255) : 0;
        wb = ((b.x >> 8) == e) ? (b.x & 255) : 0;
        d = wa - wb; s += d * d;
        wa = ((a.y >> 8) == e) ? (a.y & 255) : 0;
        wb = ((b.y >> 8) == e) ? (b.y & 255) : 0;
        d = wa - wb; s += d * d;
        wa = ((a.z >> 8) == e) ? (a.z & 255) : 0;
        wb = ((b.z >> 8) == e) ? (b.z & 255) : 0;
        d = wa - wb; s += d * d;
        wa = ((a.w >> 8) == e) ? (a.w & 255) : 0;
        wb = ((b.w >> 8) == e) ? (b.w & 255) : 0;
        d = wa - wb; s += d * d;
        // no rezero, no second barrier: next iteration's scatter targets
        // the OTHER region; this region is next written by scatter(r+2),
        // which is ordered behind barrier r+1.
    }

    // exact int32 block reduction: wave shuffle tree + 4-way LDS combine
    for (int off = 32; off > 0; off >>= 1) s += __shfl_down(s, off, 64);
    if ((tid & 63) == 0) wsum[tid >> 6] = s;
    __syncthreads();
    if (tid == 0)
        partials[blockIdx.x] = wsum[0] + wsum[1] + wsum[2] + wsum[3];
}

// Deterministic final reduction: 2048 exact int partials -> double -> mean.
__global__ __launch_bounds__(256) void reduce_partials(
    const int* __restrict__ partials,
    float* __restrict__ out)
{
    __shared__ double wave_sums[4];
    const int tid = threadIdx.x;
    const int4* p4 = (const int4*)partials;   // 2048 ints = 512 int4
    const int4 u = p4[tid & 255];
    const int4 v = p4[256 + (tid & 255)];
    double s = (double)u.x + (double)u.y + (double)u.z + (double)u.w
             + (double)v.x + (double)v.y + (double)v.z + (double)v.w;
    for (int off = 32; off > 0; off >>= 1) s += __shfl_down(s, off, 64);
    if ((tid & 63) == 0) wave_sums[tid >> 6] = s;
    __syncthreads();
    if (tid == 0) {
        double tot = wave_sums[0] + wave_sums[1] + wave_sums[2] + wave_sums[3];
        out[0] = (float)(tot / TOTAL_ELEMS);
    }
}

extern "C" void kernel_launch(void* const* d_in, const int* in_sizes, int n_in,
                              void* d_out, int out_size, void* d_ws, size_t ws_size,
                              hipStream_t stream)
{
    const float* rec = (const float*)d_in[0];
    const float* tgt = (const float*)d_in[1];
    float* out = (float*)d_out;
    int* partials = (int*)d_ws;                // NBLOCKS * 4 = 8 KiB

    holo_block_loss<<<NBLOCKS, 256, 0, stream>>>(rec, tgt, partials);
    reduce_partials<<<1, 256, 0, stream>>>(partials, out);
}